// Round 6
// baseline (1030.434 us; speedup 1.0000x reference)
//
#include <hip/hip_runtime.h>

#define HW 65536
#define CDIM 512
#define NN 50
#define NROWS 51

__device__ __forceinline__ float wave_sum(float v) {
#pragma unroll
  for (int off = 32; off; off >>= 1) v += __shfl_xor(v, off, 64);
  return v;
}
__device__ __forceinline__ float wave_max(float v) {
#pragma unroll
  for (int off = 32; off; off >>= 1) v = fmaxf(v, __shfl_xor(v, off, 64));
  return v;
}
__device__ __forceinline__ int wave_max_i(int v) {
#pragma unroll
  for (int off = 32; off; off >>= 1) v = max(v, __shfl_xor(v, off, 64));
  return v;
}
__device__ __forceinline__ int wave_min_i(int v) {
#pragma unroll
  for (int off = 32; off; off >>= 1) v = min(v, __shfl_xor(v, off, 64));
  return v;
}

// ---- grid barrier (counting; slots zeroed by k_segrank's rank block) ----
__device__ __forceinline__ void gbar(int* bar, int id, int nblk) {
  __syncthreads();
  if (threadIdx.x == 0) {
    __hip_atomic_fetch_add(&bar[id], 1, __ATOMIC_ACQ_REL, __HIP_MEMORY_SCOPE_AGENT);
    while (__hip_atomic_load(&bar[id], __ATOMIC_ACQUIRE, __HIP_MEMORY_SCOPE_AGENT) < nblk)
      __builtin_amdgcn_s_sleep(8);
  }
  __syncthreads();
}

// ==== K1: rank prologue (block (0,0)) + heavy segment-sum pass ===========
// meta: [0]=L, [52..101]=cnt, [102..151]=extra-pixel flag
__global__ __launch_bounds__(256, 4) void k_segrank(
    const float* __restrict__ fts, const int* __restrict__ msk,
    int* __restrict__ meta, int* __restrict__ P, unsigned char* __restrict__ bin8,
    float* __restrict__ seg, int* __restrict__ bar, int* __restrict__ flag) {
  int t = threadIdx.x, lane = t & 63, wv = t >> 6;
  __shared__ int sst[NN + 1];
  __shared__ int wtot[4];

  if (blockIdx.x == 0 && blockIdx.y == 0) {
    // ---- rank producer: thread t owns pixels [t*256, (t+1)*256) ----------
    const int4* m4 = (const int4*)msk;  // 16384 int4
    int cnt = 0;
#pragma unroll 8
    for (int j = 0; j < 64; ++j) {
      int4 mm = m4[t * 64 + j];
      cnt += (mm.x != 0) + (mm.y != 0) + (mm.z != 0) + (mm.w != 0);
    }
    int x = cnt;
#pragma unroll
    for (int d = 1; d < 64; d <<= 1) {
      int y = __shfl_up(x, d, 64);
      if (lane >= d) x += y;
    }
    if (lane == 63) wtot[wv] = x;
    __syncthreads();
    int base = x - cnt;
    for (int u = 0; u < wv; ++u) base += wtot[u];
    int L = wtot[0] + wtot[1] + wtot[2] + wtot[3];
    if (t <= NN) sst[t] = (int)((long long)t * L / NN);
    if (t == 0) meta[0] = L;
    if (t < NN) {
      long long Ll = L;
      int s = (int)((long long)t * Ll / NN);
      int e = (int)(((long long)(t + 1) * Ll + NN - 1) / NN);
      int ci = (int)(((long long)t * Ll + NN - 1) / NN);
      meta[2 + NN + t] = e - s;
      meta[2 + 2 * NN + t] = (t >= 1 && ci > s) ? 1 : 0;
    }
    __syncthreads();
    int r = base;
    int bi = 0;
    if (L > 0) {
      long long b0 = (long long)NN * (long long)(r < L ? r : L - 1) / L;
      bi = (int)b0;
      if (bi > NN - 1) bi = NN - 1;
      if (bi < 0) bi = 0;
    }
#pragma unroll 2
    for (int j = 0; j < 64; ++j) {
      int4 mm = m4[t * 64 + j];
      int p0 = t * 256 + j * 4;
      int f[4] = {mm.x != 0, mm.y != 0, mm.z != 0, mm.w != 0};
      unsigned char bq[4];
#pragma unroll
      for (int q = 0; q < 4; ++q) {
        bq[q] = 255;
        if (f[q]) {
          while (bi < NN - 1 && r >= sst[bi + 1]) ++bi;
          bq[q] = (unsigned char)bi;
          if (sst[bi] == r) P[bi] = p0 + q;
          if (bi + 1 < NN && sst[bi + 1] == r) P[bi + 1] = p0 + q;
          ++r;
        }
      }
      *(uchar4*)(bin8 + p0) = make_uchar4(bq[0], bq[1], bq[2], bq[3]);
    }
    // zero seg + tail barriers, then publish
    for (int i = t; i < NN * CDIM / 4; i += 256)
      ((float4*)seg)[i] = make_float4(0.f, 0.f, 0.f, 0.f);
    if (t < 8) bar[t] = 0;
    __syncthreads();
    if (t == 0) __hip_atomic_store(flag, 1, __ATOMIC_RELEASE, __HIP_MEMORY_SCOPE_AGENT);
  } else {
    if (t == 0) {
      while (__hip_atomic_load(flag, __ATOMIC_ACQUIRE, __HIP_MEMORY_SCOPE_AGENT) != 1)
        __builtin_amdgcn_s_sleep(8);
    }
    __syncthreads();
  }

  // ---- seg phase: 512-px windows, masks as 0/1 floats, pure FMA ---------
  int pb = blockIdx.x * 512;
  int cw = blockIdx.y * 64 + wv * 16;
  uchar4 u0 = *(const uchar4*)(bin8 + pb + lane * 4);
  uchar4 u1 = *(const uchar4*)(bin8 + pb + 256 + lane * 4);
  int bb[8] = {u0.x, u0.y, u0.z, u0.w, u1.x, u1.y, u1.z, u1.w};
  int mn = 255, mx = -1;
#pragma unroll
  for (int j = 0; j < 8; ++j)
    if (bb[j] != 255) { mn = min(mn, bb[j]); mx = max(mx, bb[j]); }
  mn = wave_min_i(mn);
  mx = wave_max_i(mx);
  if (mx < 0) return;
  int span = mx - mn;
  const float* base = fts + (size_t)cw * HW + pb + lane * 4;
  if (span <= 1) {
    float mlo[8], mhi[8];
#pragma unroll
    for (int j = 0; j < 8; ++j) {
      mlo[j] = (bb[j] == mn) ? 1.f : 0.f;
      mhi[j] = (bb[j] == mx) ? 1.f : 0.f;
    }
    float alo[16], ahi[16];
#pragma unroll
    for (int cs = 0; cs < 16; ++cs) { alo[cs] = 0.f; ahi[cs] = 0.f; }
    if (span == 0) {
#pragma unroll 4
      for (int cs = 0; cs < 16; ++cs) {
        const float* p = base + (size_t)cs * HW;
        float4 v0 = *(const float4*)p;
        float4 v1 = *(const float4*)(p + 256);
        alo[cs] = v0.x * mlo[0] + v0.y * mlo[1] + v0.z * mlo[2] + v0.w * mlo[3] +
                  v1.x * mlo[4] + v1.y * mlo[5] + v1.z * mlo[6] + v1.w * mlo[7];
      }
    } else {
#pragma unroll 4
      for (int cs = 0; cs < 16; ++cs) {
        const float* p = base + (size_t)cs * HW;
        float4 v0 = *(const float4*)p;
        float4 v1 = *(const float4*)(p + 256);
        alo[cs] = v0.x * mlo[0] + v0.y * mlo[1] + v0.z * mlo[2] + v0.w * mlo[3] +
                  v1.x * mlo[4] + v1.y * mlo[5] + v1.z * mlo[6] + v1.w * mlo[7];
        ahi[cs] = v0.x * mhi[0] + v0.y * mhi[1] + v0.z * mhi[2] + v0.w * mhi[3] +
                  v1.x * mhi[4] + v1.y * mhi[5] + v1.z * mhi[6] + v1.w * mhi[7];
      }
    }
#pragma unroll 1
    for (int cs = 0; cs < 16; ++cs) {
      float s = wave_sum(alo[cs]);
      if (lane == 0 && s != 0.f) atomicAdd(&seg[mn * CDIM + cw + cs], s);
    }
    if (span == 1) {
#pragma unroll 1
      for (int cs = 0; cs < 16; ++cs) {
        float s = wave_sum(ahi[cs]);
        if (lane == 0 && s != 0.f) atomicAdd(&seg[mx * CDIM + cw + cs], s);
      }
    }
  } else {
#pragma unroll 1
    for (int cs = 0; cs < 16; ++cs) {
      const float* p = base + (size_t)cs * HW;
      float4 v0 = *(const float4*)p;
      float4 v1 = *(const float4*)(p + 256);
      float vs[8] = {v0.x, v0.y, v0.z, v0.w, v1.x, v1.y, v1.z, v1.w};
#pragma unroll
      for (int j = 0; j < 8; ++j)
        if (bb[j] != 255) atomicAdd(&seg[bb[j] * CDIM + cw + cs], vs[j]);
    }
  }
}

// ==== K2: fused tail (no transposes; wave-dot matvecs on row-major W) ====
__global__ __launch_bounds__(512) void k_tail(
    const float* __restrict__ fts, const float* __restrict__ seg,
    const int* __restrict__ meta, const int* __restrict__ P,
    const float* __restrict__ g0, const float* __restrict__ g1,
    const float* __restrict__ qw, const float* __restrict__ kw,
    const float* __restrict__ vw, const float* __restrict__ mw,
    const float* __restrict__ gcn_b,
    const float* __restrict__ qb, const float* __restrict__ kb,
    const float* __restrict__ vb, const float* __restrict__ mapb,
    const float* __restrict__ gamma, const float* __restrict__ alpha,
    float* __restrict__ glob, float* __restrict__ HA, float* __restrict__ HB,
    float* __restrict__ HC, float* __restrict__ nsqA, float* __restrict__ nsqB,
    float* __restrict__ qv, float* __restrict__ kv, float* __restrict__ vv,
    float* __restrict__ out, int* __restrict__ bar) {
  int r = blockIdx.x;            // 0..50
  int t = threadIdx.x;           // 0..511
  int lane = t & 63, w = t >> 6; // 8 waves
  __shared__ float sHa[CDIM];
  __shared__ float sHn[CDIM];
  __shared__ float sagg[CDIM];
  __shared__ float sadj[64];
  __shared__ float wsum[8];

  // ---- stage A: build H row r, glob, nsqA -------------------------------
  {
    int L = meta[0];
    int c = t;
    float h;
    if (r == 0) {
      float s = 0.f;
#pragma unroll 5
      for (int i = 0; i < NN; ++i) s += seg[i * CDIM + c];
      h = s / ((float)L + 1e-8f);
      glob[c] = h;
    } else {
      int i = r - 1;
      float s = seg[i * CDIM + c];
      if (meta[2 + 2 * NN + i]) s += fts[(size_t)c * HW + P[i]];
      h = s / fmaxf((float)meta[2 + NN + i], 1.f);
    }
    HA[r * CDIM + c] = h;
    float nl = wave_sum(h * h);
    if (lane == 0) wsum[w] = nl;
    __syncthreads();
    if (t == 0) {
      float s = 0.f;
#pragma unroll
      for (int i = 0; i < 8; ++i) s += wsum[i];
      nsqA[r] = s;
    }
  }
  gbar(bar, 0, NROWS);

  // ---- stages B, C: two GCN layers --------------------------------------
#pragma unroll 1
  for (int l = 0; l < 2; ++l) {
    const float* Hin = l ? HB : HA;
    float* Hout = l ? HC : HB;
    const float* nsq = l ? nsqB : nsqA;
    float* nsqOut = l ? nsqA : nsqB;
    const float* W = l ? g1 : g0;     // [out][in] row-major, no transpose
    const float* bias = gcn_b + l * CDIM;
    sHa[t] = Hin[r * CDIM + t];
    __syncthreads();
    float na = fmaxf(sqrtf(nsq[r]), 1e-12f);
    for (int b = w; b < NROWS; b += 8) {
      const float* hb = Hin + b * CDIM;
      float d = 0.f;
#pragma unroll
      for (int k = 0; k < 8; ++k) d += sHa[lane + k * 64] * hb[lane + k * 64];
      d = wave_sum(d);
      if (lane == 0) {
        float nb = fmaxf(sqrtf(nsq[b]), 1e-12f);
        sadj[b] = fmaxf(d / (na * nb), 0.f);
      }
    }
    __syncthreads();
    if (t < 64) {
      float sv = (t < NROWS) ? sadj[t] : -1e30f;
      float m = wave_max(sv);
      float e = (t < NROWS) ? expf(sv - m) : 0.f;
      float su = wave_sum(e);
      if (t < NROWS) sadj[t] = e / su;
    }
    __syncthreads();
    {
      float acc = 0.f;
#pragma unroll 3
      for (int b = 0; b < NROWS; ++b) acc += sadj[b] * Hin[b * CDIM + t];
      sagg[t] = acc;
    }
    __syncthreads();
    // matvec: wave-dot per output c over W row c (coalesced)
    float nl = 0.f;
#pragma unroll 2
    for (int i = 0; i < 64; ++i) {
      int c = w * 64 + i;
      const float* wr = W + (size_t)c * CDIM;
      float d = 0.f;
#pragma unroll
      for (int k = 0; k < 8; ++k) d += wr[lane + k * 64] * sagg[lane + k * 64];
      d = wave_sum(d);
      float h = sHa[c] + fmaxf(bias[c] + d, 0.f);
      if (lane == (i & 63)) {
        Hout[r * CDIM + c] = h;
        sHn[c] = h;
        nl += h * h;
      }
    }
    nl = wave_sum(nl);
    if (lane == 0) wsum[w] = nl;
    __syncthreads();
    if (t == 0) {
      float s = 0.f;
#pragma unroll
      for (int i = 0; i < 8; ++i) s += wsum[i];
      nsqOut[r] = s;
    }
    if (l == 0) gbar(bar, 1, NROWS);
  }
  __syncthreads();  // sHn complete (own row of HC)

  // ---- stage D: q,k,v projections (needs only own row, in sHn) ----------
  if (r == 0) {
#pragma unroll 2
    for (int i = 0; i < 32; ++i) {
      int c = w * 32 + i;
      const float* wr = qw + (size_t)c * CDIM;
      float d = 0.f;
#pragma unroll
      for (int k = 0; k < 8; ++k) d += wr[lane + k * 64] * sHn[lane + k * 64];
      d = wave_sum(d);
      if (lane == 0) qv[c] = qb[c] + d;
    }
  } else {
    int i0 = r - 1;
#pragma unroll 2
    for (int i = 0; i < 32; ++i) {
      int c = w * 32 + i;
      const float* wr = kw + (size_t)c * CDIM;
      float d = 0.f;
#pragma unroll
      for (int k = 0; k < 8; ++k) d += wr[lane + k * 64] * sHn[lane + k * 64];
      d = wave_sum(d);
      if (lane == 0) kv[i0 * 256 + c] = kb[c] + d;
    }
#pragma unroll 2
    for (int i = 0; i < 64; ++i) {
      int c = w * 64 + i;
      const float* wr = vw + (size_t)c * CDIM;
      float d = 0.f;
#pragma unroll
      for (int k = 0; k < 8; ++k) d += wr[lane + k * 64] * sHn[lane + k * 64];
      d = wave_sum(d);
      if (lane == 0) vv[i0 * CDIM + c] = vb[c] + d;
    }
  }
  gbar(bar, 3, NROWS);
  if (r >= 8) return;

  // ---- stage E: attention + map + blend (blocks 0..7, 64 outputs each) --
  for (int i = w; i < NN; i += 8) {
    float d = 0.f;
#pragma unroll
    for (int k = 0; k < 4; ++k) d += qv[lane + k * 64] * kv[i * 256 + lane + k * 64];
    d = wave_sum(d);
    if (lane == 0) sadj[i] = d * (1.f / 16.f);
  }
  __syncthreads();
  if (t < 64) {
    float sv = (t < NN) ? sadj[t] : -1e30f;
    float m = wave_max(sv);
    float e = (t < NN) ? expf(sv - m) : 0.f;
    float su = wave_sum(e);
    if (t < NN) sadj[t] = e / su;
  }
  __syncthreads();
  {
    float acc = 0.f;
#pragma unroll 5
    for (int i = 0; i < NN; ++i) acc += sadj[i] * vv[i * CDIM + t];
    sagg[t] = acc;
  }
  __syncthreads();
#pragma unroll 2
  for (int i = 0; i < 8; ++i) {
    int c = r * 64 + w * 8 + i;
    const float* wr = mw + (size_t)c * CDIM;
    float d = 0.f;
#pragma unroll
    for (int k = 0; k < 8; ++k) d += wr[lane + k * 64] * sagg[lane + k * 64];
    d = wave_sum(d);
    if (lane == 0) {
      float o = mapb[c] + d;
      float wv_ = 1.f / (1.f + expf(-alpha[0]));
      float fp = HC[c] + gamma[0] * o;  // HC row 0 == q_node
      out[c] = glob[c] * (1.f - wv_) + fp * wv_;
    }
  }
}

// -------------------------------------------------------------------------
extern "C" void kernel_launch(void* const* d_in, const int* in_sizes, int n_in,
                              void* d_out, int out_size, void* d_ws, size_t ws_size,
                              hipStream_t stream) {
  const float* fts = (const float*)d_in[0];
  const int* msk = (const int*)d_in[1];
  const float* gcn_w = (const float*)d_in[2];
  const float* gcn_b = (const float*)d_in[3];
  const float* q_w = (const float*)d_in[4];
  const float* q_b = (const float*)d_in[5];
  const float* k_w = (const float*)d_in[6];
  const float* k_b = (const float*)d_in[7];
  const float* v_w = (const float*)d_in[8];
  const float* v_b = (const float*)d_in[9];
  const float* map_w = (const float*)d_in[10];
  const float* map_b = (const float*)d_in[11];
  const float* gamma = (const float*)d_in[12];
  const float* alpha = (const float*)d_in[13];
  float* out = (float*)d_out;

  char* wp = (char*)d_ws;
  auto alloc = [&](size_t bytes) {
    char* p = wp;
    wp += (bytes + 255) & ~(size_t)255;
    return p;
  };
  int* meta = (int*)alloc(160 * 4);
  int* P = (int*)alloc(NN * 4);
  unsigned char* bin8 = (unsigned char*)alloc(HW);
  float* seg = (float*)alloc(NN * CDIM * 4);
  float* glob = (float*)alloc(CDIM * 4);
  float* HA = (float*)alloc(NROWS * CDIM * 4);
  float* HB = (float*)alloc(NROWS * CDIM * 4);
  float* HC = (float*)alloc(NROWS * CDIM * 4);
  float* nsqA = (float*)alloc(NROWS * 4);
  float* nsqB = (float*)alloc(NROWS * 4);
  float* qv = (float*)alloc(256 * 4);
  float* kv = (float*)alloc(NN * 256 * 4);
  float* vv = (float*)alloc(NN * CDIM * 4);
  int* bar = (int*)alloc(8 * 4);
  int* flag = (int*)alloc(4);

  k_segrank<<<dim3(128, 8), 256, 0, stream>>>(fts, msk, meta, P, bin8, seg, bar, flag);
  k_tail<<<NROWS, 512, 0, stream>>>(
      fts, seg, meta, P, gcn_w, gcn_w + 512 * 512, q_w, k_w, v_w, map_w,
      gcn_b, q_b, k_b, v_b, map_b, gamma, alpha,
      glob, HA, HB, HC, nsqA, nsqB, qv, kv, vv, out, bar);
}